// Round 1
// baseline (736.140 us; speedup 1.0000x reference)
//
#include <hip/hip_runtime.h>
#include <cfloat>
#include <cstdint>

#define AN 100000   // anchors
#define GN 512      // ground truths
#define NC 80       // classes
#define KK 13       // topk

__device__ __forceinline__ float metric_f(
    float gx1, float gy1, float gx2, float gy2, float ga,
    float px1, float py1, float px2, float py2, float pa,
    float score)
{
    float ltx = fmaxf(gx1, px1), lty = fmaxf(gy1, py1);
    float rbx = fminf(gx2, px2), rby = fminf(gy2, py2);
    float w = fmaxf(rbx - ltx, 0.0f), h = fmaxf(rby - lty, 0.0f);
    float inter = w * h;
    float uni = ga + pa - inter;
    float iou = inter / (uni + 1e-9f);
    float i2 = iou * iou;
    float i6 = i2 * i2 * i2;
    return score * i6;   // scores ** 1.0 * ious ** 6.0
}

// pd_scores [AN][NC] -> scT [NC][AN], LDS-tiled so both sides are coalesced.
__global__ __launch_bounds__(256) void transpose_scores(
    const float* __restrict__ ps, float* __restrict__ scT)
{
    __shared__ float tile[64][NC];          // 20 KB
    int a0 = blockIdx.x * 64;
    int tid = threadIdx.x;
    // load 64 anchors x 80 classes (NC % 4 == 0 so float4 stays in-row)
    for (int i = tid; i < 64 * NC / 4; i += 256) {
        int fi = i * 4;
        int a = fi / NC, c = fi % NC;
        if (a0 + a < AN) {
            float4 v = *reinterpret_cast<const float4*>(ps + (size_t)(a0 + a) * NC + c);
            tile[a][c] = v.x; tile[a][c + 1] = v.y; tile[a][c + 2] = v.z; tile[a][c + 3] = v.w;
        }
    }
    __syncthreads();
    int j = tid & 63, cg = tid >> 6;
    int a = a0 + j;
    if (a < AN) {
        for (int c = cg; c < NC; c += 4)
            scT[(size_t)c * AN + a] = tile[j][c];   // coalesced 256B/wave stores
    }
}

// One thread per anchor: max/argmax over g, then write labels/bboxes/max_metrics.
__global__ __launch_bounds__(256) void argmax_kernel(
    const float* __restrict__ pd_scores,
    const float* __restrict__ pd_bboxes,
    const int*   __restrict__ gt_labels,
    const float* __restrict__ gt_bboxes,
    const float* __restrict__ scT, int use_t,
    float* __restrict__ out)
{
    __shared__ float4 gb[GN];
    __shared__ float  ga[GN];
    __shared__ int    gl[GN];
    int tid = threadIdx.x;
    for (int g = tid; g < GN; g += 256) {
        float4 b = reinterpret_cast<const float4*>(gt_bboxes)[g];
        gb[g] = b;
        ga[g] = (b.z - b.x) * (b.w - b.y);
        gl[g] = gt_labels[g];
    }
    __syncthreads();
    int a = blockIdx.x * 256 + tid;
    if (a >= AN) return;

    float4 pb = reinterpret_cast<const float4*>(pd_bboxes)[a];
    float pa = (pb.z - pb.x) * (pb.w - pb.y);

    float best = -1.0f;   // metrics are always >= 0, so g=0 always wins first
    int bg = 0;
    for (int g = 0; g < GN; ++g) {
        int lab = gl[g];
        float sc = use_t ? scT[(size_t)lab * AN + a]
                         : pd_scores[(size_t)a * NC + lab];
        float4 gbx = gb[g];
        float m = metric_f(gbx.x, gbx.y, gbx.z, gbx.w, ga[g],
                           pb.x, pb.y, pb.z, pb.w, pa, sc);
        if (m > best) { best = m; bg = g; }   // strict > => first-occurrence argmax
    }

    float lblf = (best <= 0.0f) ? (float)NC : (float)gl[bg];
    out[a] = lblf;                                      // target_labels
    reinterpret_cast<float4*>(out + AN)[a] = gb[bg];    // target_bboxes
    out[5 * AN + a] = best;                             // max_metrics
}

// One block per gt row: exact top-13 (desc value, asc index) then scatter ones.
__global__ __launch_bounds__(256) void topk_kernel(
    const float* __restrict__ pd_scores,
    const float* __restrict__ pd_bboxes,
    const int*   __restrict__ gt_labels,
    const float* __restrict__ gt_bboxes,
    const float* __restrict__ scT, int use_t,
    float* __restrict__ mask)
{
    __shared__ float sv[256 * KK];
    __shared__ int   si[256 * KK];
    int g = blockIdx.x, tid = threadIdx.x;
    float4 b = reinterpret_cast<const float4*>(gt_bboxes)[g];
    float gax = (b.z - b.x) * (b.w - b.y);
    int lab = gt_labels[g];

    float v[KK]; int idx[KK];
    #pragma unroll
    for (int j = 0; j < KK; ++j) { v[j] = -FLT_MAX; idx[j] = 0x7fffffff; }

    for (int a = tid; a < AN; a += 256) {
        float4 pb = reinterpret_cast<const float4*>(pd_bboxes)[a];
        float pa = (pb.z - pb.x) * (pb.w - pb.y);
        float sc = use_t ? scT[(size_t)lab * AN + a]
                         : pd_scores[(size_t)a * NC + lab];
        float m = metric_f(b.x, b.y, b.z, b.w, gax,
                           pb.x, pb.y, pb.z, pb.w, pa, sc);
        // strict >: an equal value never displaces an earlier (smaller) index
        if (m > v[KK - 1]) {
            int p = 0;
            #pragma unroll
            for (int j = 0; j < KK; ++j) p += (v[j] >= m) ? 1 : 0;
            #pragma unroll
            for (int j = KK - 1; j > 0; --j) {
                bool sh = (v[j - 1] < m);
                v[j]   = sh ? v[j - 1]   : v[j];
                idx[j] = sh ? idx[j - 1] : idx[j];
            }
            #pragma unroll
            for (int j = 0; j < KK; ++j) if (j == p) { v[j] = m; idx[j] = a; }
        }
    }

    #pragma unroll
    for (int j = 0; j < KK; ++j) { sv[tid * KK + j] = v[j]; si[tid * KK + j] = idx[j]; }

    // tree-merge 256 sorted 13-lists; comparator = (value desc, index asc)
    for (int off = 128; off >= 1; off >>= 1) {
        __syncthreads();
        if (tid < off) {
            int i = 0, jj = 0;
            float ov[KK]; int oi[KK];
            #pragma unroll
            for (int t = 0; t < KK; ++t) {
                float va = sv[tid * KK + i];          int ia = si[tid * KK + i];
                float vb = sv[(tid + off) * KK + jj]; int ib = si[(tid + off) * KK + jj];
                bool ta = (va > vb) || (va == vb && ia < ib);
                ov[t] = ta ? va : vb; oi[t] = ta ? ia : ib;
                i += ta ? 1 : 0; jj += ta ? 0 : 1;
            }
            #pragma unroll
            for (int t = 0; t < KK; ++t) { sv[tid * KK + t] = ov[t]; si[tid * KK + t] = oi[t]; }
        }
    }
    __syncthreads();
    if (tid < KK) mask[(size_t)g * AN + si[tid]] = 1.0f;
}

extern "C" void kernel_launch(void* const* d_in, const int* in_sizes, int n_in,
                              void* d_out, int out_size, void* d_ws, size_t ws_size,
                              hipStream_t stream)
{
    const float* pd_scores = (const float*)d_in[0];
    const float* pd_bboxes = (const float*)d_in[1];
    const int*   gt_labels = (const int*)d_in[2];   // integer inputs arrive as int32
    const float* gt_bboxes = (const float*)d_in[3];
    float* out  = (float*)d_out;
    float* mask = out + (size_t)6 * AN;             // is_in_topk region [GN][AN]

    // zero the mask region; topk_kernel scatters the 13 ones per row afterwards
    hipMemsetAsync(mask, 0, (size_t)GN * AN * sizeof(float), stream);

    int use_t = (ws_size >= (size_t)NC * AN * sizeof(float)) ? 1 : 0;
    float* scT = (float*)d_ws;
    if (use_t)
        transpose_scores<<<(AN + 63) / 64, 256, 0, stream>>>(pd_scores, scT);

    argmax_kernel<<<(AN + 255) / 256, 256, 0, stream>>>(
        pd_scores, pd_bboxes, gt_labels, gt_bboxes, scT, use_t, out);

    topk_kernel<<<GN, 256, 0, stream>>>(
        pd_scores, pd_bboxes, gt_labels, gt_bboxes, scT, use_t, mask);
}

// Round 2
// 384.599 us; speedup vs baseline: 1.9140x; 1.9140x over previous
//
#include <hip/hip_runtime.h>
#include <cfloat>
#include <cstdint>

#define AN 100000   // anchors
#define GN 512      // ground truths
#define NC 80       // classes
#define KK 13       // topk

#define CHUNKS 16
#define CHUNK_LEN (AN / CHUNKS)   // 6250
#define CAND_CAP 640              // >= 384 (flush trigger) + 256 (max appends/window)

__device__ __forceinline__ float metric_f(
    float gx1, float gy1, float gx2, float gy2, float ga,
    float px1, float py1, float px2, float py2, float pa,
    float score)
{
    float ltx = fmaxf(gx1, px1), lty = fmaxf(gy1, py1);
    float rbx = fminf(gx2, px2), rby = fminf(gy2, py2);
    float w = fmaxf(rbx - ltx, 0.0f), h = fmaxf(rby - lty, 0.0f);
    float inter = w * h;
    float uni = ga + pa - inter;
    float iou = inter / (uni + 1e-9f);
    float i2 = iou * iou;
    float i6 = i2 * i2 * i2;
    return score * i6;   // scores ** 1.0 * ious ** 6.0
}

// Insert (m, a) into a register-resident sorted-13 list.
// Order: value desc, index asc (lax.top_k tie semantics). Exact.
__device__ __forceinline__ void insert13(float* v, int* ix, float m, int a)
{
    bool worse = (m < v[KK - 1]) || (m == v[KK - 1] && a > ix[KK - 1]);
    if (worse) return;
    int p = 0;
    #pragma unroll
    for (int j = 0; j < KK; ++j)
        p += ((v[j] > m) || (v[j] == m && ix[j] < a)) ? 1 : 0;
    #pragma unroll
    for (int j = KK - 1; j >= 1; --j) {
        bool sh = (j > p);
        v[j]  = sh ? v[j - 1]  : v[j];
        ix[j] = sh ? ix[j - 1] : ix[j];
    }
    #pragma unroll
    for (int j = 0; j < KK; ++j) if (j == p) { v[j] = m; ix[j] = a; }
}

// Tree-merge 64 sorted 13-lists living in msv/msi; result in msv[0..12].
__device__ __forceinline__ void wave_merge13(float* msv, int* msi, int lane,
                                             const float* v, const int* ix)
{
    #pragma unroll
    for (int j = 0; j < KK; ++j) { msv[lane * KK + j] = v[j]; msi[lane * KK + j] = ix[j]; }
    __syncthreads();
    for (int off = 32; off >= 1; off >>= 1) {
        if (lane < off) {
            int i = 0, jj = 0;
            float ov[KK]; int oi[KK];
            #pragma unroll
            for (int t = 0; t < KK; ++t) {
                float va = msv[lane * KK + i];          int ia = msi[lane * KK + i];
                float vb = msv[(lane + off) * KK + jj]; int ib = msi[(lane + off) * KK + jj];
                bool ta = (va > vb) || (va == vb && ia < ib);
                ov[t] = ta ? va : vb; oi[t] = ta ? ia : ib;
                i += ta ? 1 : 0; jj += ta ? 0 : 1;
            }
            #pragma unroll
            for (int t = 0; t < KK; ++t) { msv[lane * KK + t] = ov[t]; msi[lane * KK + t] = oi[t]; }
        }
        __syncthreads();
    }
}

// Exact top-13 of {g13 ∪ candidate buffer}; updates g13, returns new threshold.
__device__ __forceinline__ float do_flush(int lane, int n,
                                          const float* cand_v, const int* cand_i,
                                          float* g13v, int* g13i,
                                          float* msv, int* msi)
{
    float v[KK]; int ix[KK];
    #pragma unroll
    for (int j = 0; j < KK; ++j) { v[j] = -FLT_MAX; ix[j] = 0x7fffffff; }
    for (int j = lane; j < n; j += 64) insert13(v, ix, cand_v[j], cand_i[j]);
    if (lane < KK) insert13(v, ix, g13v[lane], g13i[lane]);
    __syncthreads();                    // cand/g13 reads done before scratch reuse
    wave_merge13(msv, msi, lane, v, ix);
    if (lane < KK) { g13v[lane] = msv[lane]; g13i[lane] = msi[lane]; }
    __syncthreads();
    return msv[KK - 1];
}

// ---------------- pd_scores [AN][NC] -> scT [NC][AN] ----------------
__global__ __launch_bounds__(256) void transpose_scores(
    const float* __restrict__ ps, float* __restrict__ scT)
{
    __shared__ float tile[64][NC];
    int a0 = blockIdx.x * 64;
    int tid = threadIdx.x;
    for (int i = tid; i < 64 * NC / 4; i += 256) {
        int fi = i * 4;
        int a = fi / NC, c = fi % NC;
        if (a0 + a < AN) {
            float4 v = *reinterpret_cast<const float4*>(ps + (size_t)(a0 + a) * NC + c);
            tile[a][c] = v.x; tile[a][c + 1] = v.y; tile[a][c + 2] = v.z; tile[a][c + 3] = v.w;
        }
    }
    __syncthreads();
    int j = tid & 63, cg = tid >> 6;
    int a = a0 + j;
    if (a < AN) {
        for (int c = cg; c < NC; c += 4)
            scT[(size_t)c * AN + a] = tile[j][c];
    }
}

// ---------------- per-anchor argmax over g ----------------
__global__ __launch_bounds__(256) void argmax_kernel(
    const float* __restrict__ pd_scores,
    const float* __restrict__ pd_bboxes,
    const int*   __restrict__ gt_labels,
    const float* __restrict__ gt_bboxes,
    const float* __restrict__ scT, int use_t,
    float* __restrict__ out)
{
    __shared__ float4 gb[GN];
    __shared__ float  ga[GN];
    __shared__ int    gl[GN];
    int tid = threadIdx.x;
    for (int g = tid; g < GN; g += 256) {
        float4 b = reinterpret_cast<const float4*>(gt_bboxes)[g];
        gb[g] = b;
        ga[g] = (b.z - b.x) * (b.w - b.y);
        gl[g] = gt_labels[g];
    }
    __syncthreads();
    int a = blockIdx.x * 256 + tid;
    if (a >= AN) return;

    float4 pb = reinterpret_cast<const float4*>(pd_bboxes)[a];
    float pa = (pb.z - pb.x) * (pb.w - pb.y);

    float best = -1.0f;
    int bg = 0;
    for (int g = 0; g < GN; ++g) {
        int lab = gl[g];
        float sc = use_t ? scT[(size_t)lab * AN + a]
                         : pd_scores[(size_t)a * NC + lab];
        float4 gbx = gb[g];
        float m = metric_f(gbx.x, gbx.y, gbx.z, gbx.w, ga[g],
                           pb.x, pb.y, pb.z, pb.w, pa, sc);
        if (m > best) { best = m; bg = g; }   // strict > => first-occurrence argmax
    }

    float lblf = (best <= 0.0f) ? (float)NC : (float)gl[bg];
    out[a] = lblf;
    reinterpret_cast<float4*>(out + AN)[a] = gb[bg];
    out[5 * AN + a] = best;
}

// ---------------- topk pass 1: per (row, chunk) exact top-13 ----------------
// One wave per block. Hot loop: metric + threshold compare + rare LDS append.
__global__ __launch_bounds__(64) void topk_pass1(
    const float* __restrict__ pd_scores,
    const float* __restrict__ pd_bboxes,
    const int*   __restrict__ gt_labels,
    const float* __restrict__ gt_bboxes,
    const float* __restrict__ scT, int use_t,
    float* __restrict__ out_v, int* __restrict__ out_i)
{
    __shared__ float cand_v[CAND_CAP];
    __shared__ int   cand_i[CAND_CAP];
    __shared__ float msv[64 * KK];
    __shared__ int   msi[64 * KK];
    __shared__ float g13v[KK];
    __shared__ int   g13i[KK];
    __shared__ int   cnt;

    int bid = blockIdx.x;
    int g = bid % GN, c = bid / GN;     // consecutive blocks share the pd_bboxes chunk
    int lane = threadIdx.x;

    if (lane == 0) cnt = 0;
    if (lane < KK) { g13v[lane] = -FLT_MAX; g13i[lane] = 0x7fffffff; }
    __syncthreads();

    float4 b = reinterpret_cast<const float4*>(gt_bboxes)[g];
    float gax = (b.z - b.x) * (b.w - b.y);
    int lab = gt_labels[g];
    const float* srow = scT + (size_t)lab * AN;

    int a0 = c * CHUNK_LEN;
    int aend = a0 + CHUNK_LEN;
    float th = -FLT_MAX;

    int step = 0;
    for (int abase = a0; abase < aend; abase += 64, ++step) {
        int a = abase + lane;
        if (a < aend) {
            float4 pb = reinterpret_cast<const float4*>(pd_bboxes)[a];
            float pa = (pb.z - pb.x) * (pb.w - pb.y);
            float sc = use_t ? srow[a] : pd_scores[(size_t)a * NC + lab];
            float m = metric_f(b.x, b.y, b.z, b.w, gax,
                               pb.x, pb.y, pb.z, pb.w, pa, sc);
            if (m >= th) {                       // >= keeps value-ties; index ties
                int slot = atomicAdd(&cnt, 1);   // resolved exactly at flush
                cand_v[slot] = m; cand_i[slot] = a;
            }
        }
        if ((step & 3) == 3) {                   // uniform condition
            __syncthreads();
            int n = cnt;
            if (n >= 384 || step == 3) {         // forced first flush sets real th
                th = do_flush(lane, n, cand_v, cand_i, g13v, g13i, msv, msi);
                if (lane == 0) cnt = 0;
                __syncthreads();
            }
        }
    }
    __syncthreads();
    {
        int n = cnt;
        do_flush(lane, n, cand_v, cand_i, g13v, g13i, msv, msi);
    }
    if (lane < KK) {
        out_v[(size_t)(g * CHUNKS + c) * KK + lane] = g13v[lane];
        out_i[(size_t)(g * CHUNKS + c) * KK + lane] = g13i[lane];
    }
}

// ---------------- topk pass 2: merge 16 chunk-winners per row, scatter ----------------
__global__ __launch_bounds__(64) void topk_merge(
    const float* __restrict__ in_v, const int* __restrict__ in_i,
    float* __restrict__ mask)
{
    __shared__ float msv[64 * KK];
    __shared__ int   msi[64 * KK];
    int g = blockIdx.x, lane = threadIdx.x;
    float v[KK]; int ix[KK];
    #pragma unroll
    for (int j = 0; j < KK; ++j) { v[j] = -FLT_MAX; ix[j] = 0x7fffffff; }
    int total = CHUNKS * KK;   // 208
    for (int j = lane; j < total; j += 64)
        insert13(v, ix, in_v[(size_t)g * total + j], in_i[(size_t)g * total + j]);
    wave_merge13(msv, msi, lane, v, ix);
    if (lane < KK) mask[(size_t)g * AN + msi[lane]] = 1.0f;
}

// ---------------- fallback: original monolithic topk (if ws too small) ----------------
__global__ __launch_bounds__(256) void topk_kernel_fallback(
    const float* __restrict__ pd_scores,
    const float* __restrict__ pd_bboxes,
    const int*   __restrict__ gt_labels,
    const float* __restrict__ gt_bboxes,
    const float* __restrict__ scT, int use_t,
    float* __restrict__ mask)
{
    __shared__ float sv[256 * KK];
    __shared__ int   si[256 * KK];
    int g = blockIdx.x, tid = threadIdx.x;
    float4 b = reinterpret_cast<const float4*>(gt_bboxes)[g];
    float gax = (b.z - b.x) * (b.w - b.y);
    int lab = gt_labels[g];

    float v[KK]; int idx[KK];
    #pragma unroll
    for (int j = 0; j < KK; ++j) { v[j] = -FLT_MAX; idx[j] = 0x7fffffff; }

    for (int a = tid; a < AN; a += 256) {
        float4 pb = reinterpret_cast<const float4*>(pd_bboxes)[a];
        float pa = (pb.z - pb.x) * (pb.w - pb.y);
        float sc = use_t ? scT[(size_t)lab * AN + a]
                         : pd_scores[(size_t)a * NC + lab];
        float m = metric_f(b.x, b.y, b.z, b.w, gax,
                           pb.x, pb.y, pb.z, pb.w, pa, sc);
        insert13(v, idx, m, a);
    }

    #pragma unroll
    for (int j = 0; j < KK; ++j) { sv[tid * KK + j] = v[j]; si[tid * KK + j] = idx[j]; }
    for (int off = 128; off >= 1; off >>= 1) {
        __syncthreads();
        if (tid < off) {
            int i = 0, jj = 0;
            float ov[KK]; int oi[KK];
            #pragma unroll
            for (int t = 0; t < KK; ++t) {
                float va = sv[tid * KK + i];          int ia = si[tid * KK + i];
                float vb = sv[(tid + off) * KK + jj]; int ib = si[(tid + off) * KK + jj];
                bool ta = (va > vb) || (va == vb && ia < ib);
                ov[t] = ta ? va : vb; oi[t] = ta ? ia : ib;
                i += ta ? 1 : 0; jj += ta ? 0 : 1;
            }
            #pragma unroll
            for (int t = 0; t < KK; ++t) { sv[tid * KK + t] = ov[t]; si[tid * KK + t] = oi[t]; }
        }
    }
    __syncthreads();
    if (tid < KK) mask[(size_t)g * AN + si[tid]] = 1.0f;
}

extern "C" void kernel_launch(void* const* d_in, const int* in_sizes, int n_in,
                              void* d_out, int out_size, void* d_ws, size_t ws_size,
                              hipStream_t stream)
{
    const float* pd_scores = (const float*)d_in[0];
    const float* pd_bboxes = (const float*)d_in[1];
    const int*   gt_labels = (const int*)d_in[2];
    const float* gt_bboxes = (const float*)d_in[3];
    float* out  = (float*)d_out;
    float* mask = out + (size_t)6 * AN;

    hipMemsetAsync(mask, 0, (size_t)GN * AN * sizeof(float), stream);

    const size_t scT_bytes = (size_t)NC * AN * sizeof(float);          // 32 MB
    const size_t aux_elems = (size_t)GN * CHUNKS * KK;                 // 106496
    const size_t aux_bytes = aux_elems * 8;                            // v + i

    int use_t = 0;
    float* scT = (float*)d_ws;
    float* aux_v = nullptr;
    int*   aux_i = nullptr;

    if (ws_size >= scT_bytes + aux_bytes) {
        use_t = 1;
        aux_v = (float*)((char*)d_ws + scT_bytes);
        aux_i = (int*)(aux_v + aux_elems);
    } else if (ws_size >= aux_bytes) {
        use_t = 0;
        aux_v = (float*)d_ws;
        aux_i = (int*)(aux_v + aux_elems);
    }

    if (use_t)
        transpose_scores<<<(AN + 63) / 64, 256, 0, stream>>>(pd_scores, scT);

    argmax_kernel<<<(AN + 255) / 256, 256, 0, stream>>>(
        pd_scores, pd_bboxes, gt_labels, gt_bboxes, scT, use_t, out);

    if (aux_v) {
        topk_pass1<<<GN * CHUNKS, 64, 0, stream>>>(
            pd_scores, pd_bboxes, gt_labels, gt_bboxes, scT, use_t, aux_v, aux_i);
        topk_merge<<<GN, 64, 0, stream>>>(aux_v, aux_i, mask);
    } else {
        int ut2 = (ws_size >= scT_bytes) ? 1 : 0;
        topk_kernel_fallback<<<GN, 256, 0, stream>>>(
            pd_scores, pd_bboxes, gt_labels, gt_bboxes, scT, ut2, mask);
    }
}

// Round 3
// 304.413 us; speedup vs baseline: 2.4182x; 1.2634x over previous
//
#include <hip/hip_runtime.h>
#include <cfloat>
#include <cstdint>

#define AN 100000   // anchors
#define GN 512      // ground truths
#define NC 80       // classes
#define KK 13       // topk

#define CHUNKS 16
#define CHUNK_LEN (AN / CHUNKS)   // 6250
#define FLUSH_N 256               // flush trigger
#define CAND_CAP 384              // FLUSH_N-1 + 128 max appends/iter

__device__ __forceinline__ float metric_f(
    float gx1, float gy1, float gx2, float gy2, float ga,
    float px1, float py1, float px2, float py2, float pa,
    float score)
{
    float ltx = fmaxf(gx1, px1), lty = fmaxf(gy1, py1);
    float rbx = fminf(gx2, px2), rby = fminf(gy2, py2);
    float w = fmaxf(rbx - ltx, 0.0f), h = fmaxf(rby - lty, 0.0f);
    float inter = w * h;
    float uni = ga + pa - inter;
    float iou = inter / (uni + 1e-9f);
    float i2 = iou * iou;
    float i6 = i2 * i2 * i2;
    return score * i6;   // scores ** 1.0 * ious ** 6.0
}

// Insert (m, a) into a register-resident sorted-13 list.
// Order: value desc, index asc (lax.top_k tie semantics). Exact.
__device__ __forceinline__ void insert13(float* v, int* ix, float m, int a)
{
    bool worse = (m < v[KK - 1]) || (m == v[KK - 1] && a > ix[KK - 1]);
    if (worse) return;
    int p = 0;
    #pragma unroll
    for (int j = 0; j < KK; ++j)
        p += ((v[j] > m) || (v[j] == m && ix[j] < a)) ? 1 : 0;
    #pragma unroll
    for (int j = KK - 1; j >= 1; --j) {
        bool sh = (j > p);
        v[j]  = sh ? v[j - 1]  : v[j];
        ix[j] = sh ? ix[j - 1] : ix[j];
    }
    #pragma unroll
    for (int j = 0; j < KK; ++j) if (j == p) { v[j] = m; ix[j] = a; }
}

// Tree-merge 64 sorted 13-lists living in msv/msi; result in msv[0..12].
__device__ __forceinline__ void wave_merge13(float* msv, int* msi, int lane,
                                             const float* v, const int* ix)
{
    #pragma unroll
    for (int j = 0; j < KK; ++j) { msv[lane * KK + j] = v[j]; msi[lane * KK + j] = ix[j]; }
    __syncthreads();
    for (int off = 32; off >= 1; off >>= 1) {
        if (lane < off) {
            int i = 0, jj = 0;
            float ov[KK]; int oi[KK];
            #pragma unroll
            for (int t = 0; t < KK; ++t) {
                float va = msv[lane * KK + i];          int ia = msi[lane * KK + i];
                float vb = msv[(lane + off) * KK + jj]; int ib = msi[(lane + off) * KK + jj];
                bool ta = (va > vb) || (va == vb && ia < ib);
                ov[t] = ta ? va : vb; oi[t] = ta ? ia : ib;
                i += ta ? 1 : 0; jj += ta ? 0 : 1;
            }
            #pragma unroll
            for (int t = 0; t < KK; ++t) { msv[lane * KK + t] = ov[t]; msi[lane * KK + t] = oi[t]; }
        }
        __syncthreads();
    }
}

// Exact top-13 of {g13 ∪ candidate buffer}; updates g13, returns new threshold.
// cand_v/cand_i ALIAS msv/msi: all cand reads complete before merge writes.
__device__ __forceinline__ float do_flush(int lane, int n,
                                          const float* cand_v, const int* cand_i,
                                          float* g13v, int* g13i,
                                          float* msv, int* msi)
{
    float v[KK]; int ix[KK];
    #pragma unroll
    for (int j = 0; j < KK; ++j) { v[j] = -FLT_MAX; ix[j] = 0x7fffffff; }
    for (int j = lane; j < n; j += 64) insert13(v, ix, cand_v[j], cand_i[j]);
    if (lane < KK) insert13(v, ix, g13v[lane], g13i[lane]);
    __syncthreads();                    // cand reads done before scratch reuse
    wave_merge13(msv, msi, lane, v, ix);
    if (lane < KK) { g13v[lane] = msv[lane]; g13i[lane] = msi[lane]; }
    float th = msv[KK - 1];
    __syncthreads();                    // th/g13 reads done before cand reuse
    return th;
}

// ---------------- pd_scores [AN][NC] -> scT [NC][AN] ----------------
__global__ __launch_bounds__(256) void transpose_scores(
    const float* __restrict__ ps, float* __restrict__ scT)
{
    __shared__ float tile[64][NC];
    int a0 = blockIdx.x * 64;
    int tid = threadIdx.x;
    for (int i = tid; i < 64 * NC / 4; i += 256) {
        int fi = i * 4;
        int a = fi / NC, c = fi % NC;
        if (a0 + a < AN) {
            float4 v = *reinterpret_cast<const float4*>(ps + (size_t)(a0 + a) * NC + c);
            tile[a][c] = v.x; tile[a][c + 1] = v.y; tile[a][c + 2] = v.z; tile[a][c + 3] = v.w;
        }
    }
    __syncthreads();
    int j = tid & 63, cg = tid >> 6;
    int a = a0 + j;
    if (a < AN) {
        for (int c = cg; c < NC; c += 4)
            scT[(size_t)c * AN + a] = tile[j][c];
    }
}

// ---------------- per-anchor argmax over g ----------------
__global__ __launch_bounds__(256) void argmax_kernel(
    const float* __restrict__ pd_scores,
    const float* __restrict__ pd_bboxes,
    const int*   __restrict__ gt_labels,
    const float* __restrict__ gt_bboxes,
    const float* __restrict__ scT, int use_t,
    float* __restrict__ out)
{
    __shared__ float4 gb[GN];
    __shared__ float  ga[GN];
    __shared__ int    gl[GN];
    int tid = threadIdx.x;
    for (int g = tid; g < GN; g += 256) {
        float4 b = reinterpret_cast<const float4*>(gt_bboxes)[g];
        gb[g] = b;
        ga[g] = (b.z - b.x) * (b.w - b.y);
        gl[g] = gt_labels[g];
    }
    __syncthreads();
    int a = blockIdx.x * 256 + tid;
    if (a >= AN) return;

    float4 pb = reinterpret_cast<const float4*>(pd_bboxes)[a];
    float pa = (pb.z - pb.x) * (pb.w - pb.y);

    float best = -1.0f;
    int bg = 0;
    for (int g = 0; g < GN; ++g) {
        int lab = gl[g];
        float sc = use_t ? scT[(size_t)lab * AN + a]
                         : pd_scores[(size_t)a * NC + lab];
        float4 gbx = gb[g];
        float m = metric_f(gbx.x, gbx.y, gbx.z, gbx.w, ga[g],
                           pb.x, pb.y, pb.z, pb.w, pa, sc);
        if (m > best) { best = m; bg = g; }   // strict > => first-occurrence argmax
    }

    float lblf = (best <= 0.0f) ? (float)NC : (float)gl[bg];
    out[a] = lblf;
    reinterpret_cast<float4*>(out + AN)[a] = gb[bg];
    out[5 * AN + a] = best;
}

// ---------------- topk pass 1: per (row, chunk) exact top-13 ----------------
// One wave per block. Ballot-based candidate append, wave-uniform cnt,
// LDS merge scratch overlaid with the candidate buffer (~6.8 KB total).
__global__ __launch_bounds__(64) void topk_pass1(
    const float* __restrict__ pd_scores,
    const float* __restrict__ pd_bboxes,
    const int*   __restrict__ gt_labels,
    const float* __restrict__ gt_bboxes,
    const float* __restrict__ scT, int use_t,
    float* __restrict__ out_v, int* __restrict__ out_i)
{
    __shared__ float msv[64 * KK];   // merge scratch; low 384 floats double as cand_v
    __shared__ int   msi[64 * KK];
    __shared__ float g13v[KK];
    __shared__ int   g13i[KK];
    float* cand_v = msv;
    int*   cand_i = msi;

    int bid = blockIdx.x;
    int g = bid % GN, c = bid / GN;   // consecutive blocks share the pd_bboxes chunk
    int lane = threadIdx.x;
    uint64_t lmask_lt = (1ull << lane) - 1ull;

    if (lane < KK) { g13v[lane] = -FLT_MAX; g13i[lane] = 0x7fffffff; }
    __syncthreads();

    float4 b = reinterpret_cast<const float4*>(gt_bboxes)[g];
    float gax = (b.z - b.x) * (b.w - b.y);
    int lab = gt_labels[g];
    const float* srow = scT + (size_t)lab * AN;

    int a0 = c * CHUNK_LEN;
    int aend = a0 + CHUNK_LEN;
    float th = -FLT_MAX;
    int cnt = 0;                      // wave-uniform (ballot-derived)

    for (int abase = a0; abase < aend; abase += 128) {
        int a1 = abase + lane;
        int a2 = abase + 64 + lane;
        int ac1 = min(a1, AN - 1);
        int ac2 = min(a2, AN - 1);
        // two independent load chains (ILP)
        float4 pb1 = reinterpret_cast<const float4*>(pd_bboxes)[ac1];
        float4 pb2 = reinterpret_cast<const float4*>(pd_bboxes)[ac2];
        float sc1 = use_t ? srow[ac1] : pd_scores[(size_t)ac1 * NC + lab];
        float sc2 = use_t ? srow[ac2] : pd_scores[(size_t)ac2 * NC + lab];
        float pa1 = (pb1.z - pb1.x) * (pb1.w - pb1.y);
        float pa2 = (pb2.z - pb2.x) * (pb2.w - pb2.y);
        float m1 = metric_f(b.x, b.y, b.z, b.w, gax,
                            pb1.x, pb1.y, pb1.z, pb1.w, pa1, sc1);
        float m2 = metric_f(b.x, b.y, b.z, b.w, gax,
                            pb2.x, pb2.y, pb2.z, pb2.w, pa2, sc2);
        bool hit1 = (a1 < aend) && (m1 >= th);   // >= keeps value-ties;
        bool hit2 = (a2 < aend) && (m2 >= th);   // order resolved exactly at flush
        uint64_t ball1 = __ballot(hit1);
        if (ball1) {
            int p = __popcll(ball1 & lmask_lt);
            if (hit1) { cand_v[cnt + p] = m1; cand_i[cnt + p] = a1; }
            cnt += __popcll(ball1);
        }
        uint64_t ball2 = __ballot(hit2);
        if (ball2) {
            int p = __popcll(ball2 & lmask_lt);
            if (hit2) { cand_v[cnt + p] = m2; cand_i[cnt + p] = a2; }
            cnt += __popcll(ball2);
        }
        if (cnt >= FLUSH_N) {         // wave-uniform
            th = do_flush(lane, cnt, cand_v, cand_i, g13v, g13i, msv, msi);
            cnt = 0;
        }
    }
    if (cnt > 0)
        do_flush(lane, cnt, cand_v, cand_i, g13v, g13i, msv, msi);

    if (lane < KK) {
        out_v[(size_t)(g * CHUNKS + c) * KK + lane] = g13v[lane];
        out_i[(size_t)(g * CHUNKS + c) * KK + lane] = g13i[lane];
    }
}

// ---------------- topk pass 2: merge 16 chunk-winners per row, scatter ----------------
__global__ __launch_bounds__(64) void topk_merge(
    const float* __restrict__ in_v, const int* __restrict__ in_i,
    float* __restrict__ mask)
{
    __shared__ float msv[64 * KK];
    __shared__ int   msi[64 * KK];
    int g = blockIdx.x, lane = threadIdx.x;
    float v[KK]; int ix[KK];
    #pragma unroll
    for (int j = 0; j < KK; ++j) { v[j] = -FLT_MAX; ix[j] = 0x7fffffff; }
    int total = CHUNKS * KK;   // 208
    for (int j = lane; j < total; j += 64)
        insert13(v, ix, in_v[(size_t)g * total + j], in_i[(size_t)g * total + j]);
    __syncthreads();
    wave_merge13(msv, msi, lane, v, ix);
    if (lane < KK) mask[(size_t)g * AN + msi[lane]] = 1.0f;
}

// ---------------- fallback: monolithic topk (if ws too small) ----------------
__global__ __launch_bounds__(256) void topk_kernel_fallback(
    const float* __restrict__ pd_scores,
    const float* __restrict__ pd_bboxes,
    const int*   __restrict__ gt_labels,
    const float* __restrict__ gt_bboxes,
    const float* __restrict__ scT, int use_t,
    float* __restrict__ mask)
{
    __shared__ float sv[256 * KK];
    __shared__ int   si[256 * KK];
    int g = blockIdx.x, tid = threadIdx.x;
    float4 b = reinterpret_cast<const float4*>(gt_bboxes)[g];
    float gax = (b.z - b.x) * (b.w - b.y);
    int lab = gt_labels[g];

    float v[KK]; int idx[KK];
    #pragma unroll
    for (int j = 0; j < KK; ++j) { v[j] = -FLT_MAX; idx[j] = 0x7fffffff; }

    for (int a = tid; a < AN; a += 256) {
        float4 pb = reinterpret_cast<const float4*>(pd_bboxes)[a];
        float pa = (pb.z - pb.x) * (pb.w - pb.y);
        float sc = use_t ? scT[(size_t)lab * AN + a]
                         : pd_scores[(size_t)a * NC + lab];
        float m = metric_f(b.x, b.y, b.z, b.w, gax,
                           pb.x, pb.y, pb.z, pb.w, pa, sc);
        insert13(v, idx, m, a);
    }

    #pragma unroll
    for (int j = 0; j < KK; ++j) { sv[tid * KK + j] = v[j]; si[tid * KK + j] = idx[j]; }
    for (int off = 128; off >= 1; off >>= 1) {
        __syncthreads();
        if (tid < off) {
            int i = 0, jj = 0;
            float ov[KK]; int oi[KK];
            #pragma unroll
            for (int t = 0; t < KK; ++t) {
                float va = sv[tid * KK + i];          int ia = si[tid * KK + i];
                float vb = sv[(tid + off) * KK + jj]; int ib = si[(tid + off) * KK + jj];
                bool ta = (va > vb) || (va == vb && ia < ib);
                ov[t] = ta ? va : vb; oi[t] = ta ? ia : ib;
                i += ta ? 1 : 0; jj += ta ? 0 : 1;
            }
            #pragma unroll
            for (int t = 0; t < KK; ++t) { sv[tid * KK + t] = ov[t]; si[tid * KK + t] = oi[t]; }
        }
    }
    __syncthreads();
    if (tid < KK) mask[(size_t)g * AN + si[tid]] = 1.0f;
}

extern "C" void kernel_launch(void* const* d_in, const int* in_sizes, int n_in,
                              void* d_out, int out_size, void* d_ws, size_t ws_size,
                              hipStream_t stream)
{
    const float* pd_scores = (const float*)d_in[0];
    const float* pd_bboxes = (const float*)d_in[1];
    const int*   gt_labels = (const int*)d_in[2];
    const float* gt_bboxes = (const float*)d_in[3];
    float* out  = (float*)d_out;
    float* mask = out + (size_t)6 * AN;

    hipMemsetAsync(mask, 0, (size_t)GN * AN * sizeof(float), stream);

    const size_t scT_bytes = (size_t)NC * AN * sizeof(float);          // 32 MB
    const size_t aux_elems = (size_t)GN * CHUNKS * KK;                 // 106496
    const size_t aux_bytes = aux_elems * 8;                            // v + i

    int use_t = 0;
    float* scT = (float*)d_ws;
    float* aux_v = nullptr;
    int*   aux_i = nullptr;

    if (ws_size >= scT_bytes + aux_bytes) {
        use_t = 1;
        aux_v = (float*)((char*)d_ws + scT_bytes);
        aux_i = (int*)(aux_v + aux_elems);
    } else if (ws_size >= aux_bytes) {
        use_t = 0;
        aux_v = (float*)d_ws;
        aux_i = (int*)(aux_v + aux_elems);
    }

    if (use_t)
        transpose_scores<<<(AN + 63) / 64, 256, 0, stream>>>(pd_scores, scT);

    argmax_kernel<<<(AN + 255) / 256, 256, 0, stream>>>(
        pd_scores, pd_bboxes, gt_labels, gt_bboxes, scT, use_t, out);

    if (aux_v) {
        topk_pass1<<<GN * CHUNKS, 64, 0, stream>>>(
            pd_scores, pd_bboxes, gt_labels, gt_bboxes, scT, use_t, aux_v, aux_i);
        topk_merge<<<GN, 64, 0, stream>>>(aux_v, aux_i, mask);
    } else {
        int ut2 = (ws_size >= scT_bytes) ? 1 : 0;
        topk_kernel_fallback<<<GN, 256, 0, stream>>>(
            pd_scores, pd_bboxes, gt_labels, gt_bboxes, scT, ut2, mask);
    }
}

// Round 4
// 285.138 us; speedup vs baseline: 2.5817x; 1.0676x over previous
//
#include <hip/hip_runtime.h>
#include <cfloat>
#include <cstdint>

#define AN 100000   // anchors
#define GN 512      // ground truths
#define NC 80       // classes
#define KK 13       // topk

#define CH_LEN 6400               // chunk length (multiple of 256)
#define CHUNKS 16                 // 15*6400 + 4000 = 100000
#define DUMP 64                   // dump slots per (g, chunk)
#define GSLICE 4
#define GPS (GN / GSLICE)         // 128

typedef unsigned long long ull;

__device__ __forceinline__ float metric_f(
    float gx1, float gy1, float gx2, float gy2, float ga,
    float px1, float py1, float px2, float py2, float pa,
    float score)
{
    float ltx = fmaxf(gx1, px1), lty = fmaxf(gy1, py1);
    float rbx = fminf(gx2, px2), rby = fminf(gy2, py2);
    float w = fmaxf(rbx - ltx, 0.0f), h = fmaxf(rby - lty, 0.0f);
    float inter = w * h;
    float uni = ga + pa - inter;
    float iou = inter / (uni + 1e-9f);
    float i2 = iou * iou;
    float i6 = i2 * i2 * i2;
    return score * i6;   // scores ** 1.0 * ious ** 6.0
}

__device__ __forceinline__ float metric2(float4 g, float ga, float4 p, float sc)
{
    float pa = (p.z - p.x) * (p.w - p.y);
    return metric_f(g.x, g.y, g.z, g.w, ga, p.x, p.y, p.z, p.w, pa, sc);
}

// Insert (m, a) into a register-resident sorted-13 list (desc value, asc index).
__device__ __forceinline__ void insert13(float* v, int* ix, float m, int a)
{
    bool worse = (m < v[KK - 1]) || (m == v[KK - 1] && a > ix[KK - 1]);
    if (worse) return;
    int p = 0;
    #pragma unroll
    for (int j = 0; j < KK; ++j)
        p += ((v[j] > m) || (v[j] == m && ix[j] < a)) ? 1 : 0;
    #pragma unroll
    for (int j = KK - 1; j >= 1; --j) {
        bool sh = (j > p);
        v[j]  = sh ? v[j - 1]  : v[j];
        ix[j] = sh ? ix[j - 1] : ix[j];
    }
    #pragma unroll
    for (int j = 0; j < KK; ++j) if (j == p) { v[j] = m; ix[j] = a; }
}

// Wave-synchronous LDS fence: single 64-lane wave runs in lockstep, so
// ds-op completion (lgkmcnt 0) + compiler ordering = cross-lane visibility.
__device__ __forceinline__ void wsync()
{
    __builtin_amdgcn_sched_barrier(0);
    asm volatile("s_waitcnt lgkmcnt(0)" ::: "memory");
    __builtin_amdgcn_sched_barrier(0);
}

// Per-wave exact top-13 of {g13 (msv[0..12]) ∪ cand (msv[64..64+n))}.
// Result lands back at msv[0..12]; returns new threshold. No s_barrier.
__device__ float flush_w(int lane, int n, float* msv, int* msi)
{
    float* cand_v = msv + DUMP;
    int*   cand_i = msi + DUMP;
    float v[KK]; int ix[KK];
    #pragma unroll
    for (int j = 0; j < KK; ++j) { v[j] = -FLT_MAX; ix[j] = 0x7fffffff; }
    wsync();                                    // appended cand visible
    for (int j = lane; j < n; j += 64) insert13(v, ix, cand_v[j], cand_i[j]);
    if (lane < KK) insert13(v, ix, msv[lane], msi[lane]);   // g13
    wsync();                                    // reads done before overwrite
    #pragma unroll
    for (int j = 0; j < KK; ++j) { msv[lane * KK + j] = v[j]; msi[lane * KK + j] = ix[j]; }
    wsync();
    for (int off = 32; off >= 1; off >>= 1) {
        if (lane < off) {
            int i = 0, jj = 0;
            float ov[KK]; int oi[KK];
            #pragma unroll
            for (int t = 0; t < KK; ++t) {
                float va = msv[lane * KK + i];          int ia = msi[lane * KK + i];
                float vb = msv[(lane + off) * KK + jj]; int ib = msi[(lane + off) * KK + jj];
                bool ta = (va > vb) || (va == vb && ia < ib);
                ov[t] = ta ? va : vb; oi[t] = ta ? ia : ib;
                i += ta ? 1 : 0; jj += ta ? 0 : 1;
            }
            #pragma unroll
            for (int t = 0; t < KK; ++t) { msv[lane * KK + t] = ov[t]; msi[lane * KK + t] = oi[t]; }
        }
        wsync();
    }
    return msv[KK - 1];
}

// Block-wide tree-merge of 64 sorted 13-lists (single-wave blocks).
__device__ __forceinline__ void wave_merge13(float* msv, int* msi, int lane,
                                             const float* v, const int* ix)
{
    #pragma unroll
    for (int j = 0; j < KK; ++j) { msv[lane * KK + j] = v[j]; msi[lane * KK + j] = ix[j]; }
    __syncthreads();
    for (int off = 32; off >= 1; off >>= 1) {
        if (lane < off) {
            int i = 0, jj = 0;
            float ov[KK]; int oi[KK];
            #pragma unroll
            for (int t = 0; t < KK; ++t) {
                float va = msv[lane * KK + i];          int ia = msi[lane * KK + i];
                float vb = msv[(lane + off) * KK + jj]; int ib = msi[(lane + off) * KK + jj];
                bool ta = (va > vb) || (va == vb && ia < ib);
                ov[t] = ta ? va : vb; oi[t] = ta ? ia : ib;
                i += ta ? 1 : 0; jj += ta ? 0 : 1;
            }
            #pragma unroll
            for (int t = 0; t < KK; ++t) { msv[lane * KK + t] = ov[t]; msi[lane * KK + t] = oi[t]; }
        }
        __syncthreads();
    }
}

// ---------------- pd_scores [AN][NC] -> scT [NC][AN] ----------------
__global__ __launch_bounds__(256) void transpose_scores(
    const float* __restrict__ ps, float* __restrict__ scT)
{
    __shared__ float tile[64][NC + 1];   // +1 pad: unpadded was a 32-way conflict
    int a0 = blockIdx.x * 64;
    int tid = threadIdx.x;
    for (int i = tid; i < 64 * NC / 4; i += 256) {
        int fi = i * 4;
        int a = fi / NC, c = fi % NC;
        if (a0 + a < AN) {
            float4 v = *reinterpret_cast<const float4*>(ps + (size_t)(a0 + a) * NC + c);
            tile[a][c] = v.x; tile[a][c + 1] = v.y; tile[a][c + 2] = v.z; tile[a][c + 3] = v.w;
        }
    }
    __syncthreads();
    int j = tid & 63, cg = tid >> 6;
    int a = a0 + j;
    if (a < AN) {
        for (int c = cg; c < NC; c += 4)
            scT[(size_t)c * AN + a] = tile[j][c];
    }
}

// ---------------- argmax pass A1: per (anchor, g-slice) partial ----------------
__global__ __launch_bounds__(256) void argmax_part(
    const float* __restrict__ pd_bboxes,
    const int*   __restrict__ gt_labels,
    const float* __restrict__ gt_bboxes,
    const float* __restrict__ scT,
    ull* __restrict__ part)
{
    __shared__ float4 gb[GPS];
    __shared__ float  ga[GPS];
    __shared__ int    glb[GPS];
    int slice = blockIdx.x & (GSLICE - 1);
    int ab = (blockIdx.x >> 2) * 256;
    int tid = threadIdx.x;
    int g0 = slice * GPS;
    for (int i = tid; i < GPS; i += 256) {
        float4 bb = ((const float4*)gt_bboxes)[g0 + i];
        gb[i] = bb;
        ga[i] = (bb.z - bb.x) * (bb.w - bb.y);
        glb[i] = gt_labels[g0 + i];
    }
    __syncthreads();
    int a = ab + tid;
    if (a >= AN) return;
    float4 pb = ((const float4*)pd_bboxes)[a];
    float pa = (pb.z - pb.x) * (pb.w - pb.y);
    float best = -1.0f; int bg = 0;
    for (int i = 0; i < GPS; ++i) {
        float sc = scT[(size_t)glb[i] * AN + a];
        float4 gx = gb[i];
        float m = metric_f(gx.x, gx.y, gx.z, gx.w, ga[i],
                           pb.x, pb.y, pb.z, pb.w, pa, sc);
        if (m > best) { best = m; bg = i; }   // strict > => first-occurrence
    }
    // pack: high = metric bits (m >= 0 so uint order == float order),
    // low = ~g so that ties pick the smallest g under u64 max.
    ull pack = ((ull)__float_as_uint(best) << 32) | (ull)(0xFFFFFFFFu - (unsigned)(g0 + bg));
    part[(size_t)slice * AN + a] = pack;
}

// ---------------- argmax pass A2: combine 4 slices, write outputs ----------------
__global__ __launch_bounds__(256) void argmax_combine(
    const ull* __restrict__ part,
    const int* __restrict__ gt_labels,
    const float* __restrict__ gt_bboxes,
    float* __restrict__ out)
{
    int a = blockIdx.x * 256 + threadIdx.x;
    if (a >= AN) return;
    ull p0 = part[a], p1 = part[(size_t)AN + a];
    ull p2 = part[(size_t)2 * AN + a], p3 = part[(size_t)3 * AN + a];
    ull q0 = p0 > p1 ? p0 : p1;
    ull q1 = p2 > p3 ? p2 : p3;
    ull p = q0 > q1 ? q0 : q1;
    unsigned g = 0xFFFFFFFFu - (unsigned)(p & 0xFFFFFFFFull);
    float best = __uint_as_float((unsigned)(p >> 32));
    out[a] = (best <= 0.0f) ? (float)NC : (float)gt_labels[g];
    ((float4*)(out + AN))[a] = ((const float4*)gt_bboxes)[g];
    out[(size_t)5 * AN + a] = best;
}

// ---------------- topk pass 1: 4 independent waves per block ----------------
template<bool FULL>
__device__ __forceinline__ void proc256(
    int tb, int rem, int lane, uint64_t lt,
    const float4* __restrict__ pd4, const float4* __restrict__ scT4,
    float4 b, float gax, float& th, int& cnt, float* msv, int* msi)
{
    float* cand_v = msv + DUMP;
    int*   cand_i = msi + DUMP;
    int a0 = tb + 4 * lane;
    float4 s4, b0, b1, b2, b3;
    if (FULL) {
        s4 = scT4[(tb >> 2) + lane];
        b0 = pd4[a0]; b1 = pd4[a0 + 1]; b2 = pd4[a0 + 2]; b3 = pd4[a0 + 3];
    } else {
        s4 = scT4[min((tb >> 2) + lane, AN / 4 - 1)];
        int ac = min(a0, AN - 4);
        b0 = pd4[ac]; b1 = pd4[ac + 1]; b2 = pd4[ac + 2]; b3 = pd4[ac + 3];
    }
    float m0 = metric2(b, gax, b0, s4.x);
    float m1 = metric2(b, gax, b1, s4.y);
    float m2 = metric2(b, gax, b2, s4.z);
    float m3 = metric2(b, gax, b3, s4.w);
    // strict >: an item equal to the current 13th value always loses the
    // index tie to the resident 13th (all resident indices are smaller),
    // so it can never enter the top-13 — dropping it is exact.
    bool h0 = m0 > th, h1 = m1 > th, h2 = m2 > th, h3 = m3 > th;
    if (!FULL) {
        int r = 4 * lane;
        h0 &= (r < rem); h1 &= (r + 1 < rem); h2 &= (r + 2 < rem); h3 &= (r + 3 < rem);
    }
    uint64_t B0 = __ballot(h0), B1 = __ballot(h1), B2 = __ballot(h2), B3 = __ballot(h3);
    if (B0 | B1 | B2 | B3) {
        if (h0) { int p = cnt + __popcll(B0 & lt); cand_v[p] = m0; cand_i[p] = a0; }
        cnt += __popcll(B0);
        if (h1) { int p = cnt + __popcll(B1 & lt); cand_v[p] = m1; cand_i[p] = a0 + 1; }
        cnt += __popcll(B1);
        if (h2) { int p = cnt + __popcll(B2 & lt); cand_v[p] = m2; cand_i[p] = a0 + 2; }
        cnt += __popcll(B2);
        if (h3) { int p = cnt + __popcll(B3 & lt); cand_v[p] = m3; cand_i[p] = a0 + 3; }
        cnt += __popcll(B3);
        if (cnt >= 256) { th = flush_w(lane, cnt, msv, msi); cnt = 0; }  // cap 256+255 < 512
    }
}

__global__ __launch_bounds__(256, 6) void topk_pass1(
    const float* __restrict__ pd_bboxes,
    const int*   __restrict__ gt_labels,
    const float* __restrict__ gt_bboxes,
    const float* __restrict__ scT,
    float* __restrict__ out_v, int* __restrict__ out_i)
{
    // per-wave 832-float scratch: [0..12] g13, [64..575] cand, [0..831] merge tree
    __shared__ float msvA[4][832];
    __shared__ int   msiA[4][832];
    int w = threadIdx.x >> 6, lane = threadIdx.x & 63;
    float* msv = msvA[w]; int* msi = msiA[w];
    uint64_t lt = (1ull << lane) - 1ull;
    int gid = blockIdx.x * 4 + w;
    int g = gid & (GN - 1), c = gid >> 9;

    if (lane < KK) { msv[lane] = -FLT_MAX; msi[lane] = 0x7fffffff; }  // same-lane reuse

    float4 b = ((const float4*)gt_bboxes)[g];
    float gax = (b.z - b.x) * (b.w - b.y);
    int lab = gt_labels[g];
    const float4* scT4 = (const float4*)(scT + (size_t)lab * AN);
    const float4* pd4  = (const float4*)pd_bboxes;

    int base = c * CH_LEN;
    int len = min(CH_LEN, AN - base);
    int nfull = len >> 8, rem = len & 255;
    float th = -FLT_MAX; int cnt = 0;

    for (int it = 0; it < nfull; ++it)
        proc256<true>(base + (it << 8), 0, lane, lt, pd4, scT4, b, gax, th, cnt, msv, msi);
    if (rem)
        proc256<false>(base + (nfull << 8), rem, lane, lt, pd4, scT4, b, gax, th, cnt, msv, msi);

    if (cnt > DUMP - KK) { flush_w(lane, cnt, msv, msi); cnt = 0; }
    wsync();
    // dump g13 + raw leftovers (exactness: every non-dumped item was < some
    // chunk-local 13 better items, so it cannot be in the row top-13)
    float dv; int di;
    if (lane < KK)            { dv = msv[lane];             di = msi[lane]; }
    else if (lane - KK < cnt) { dv = msv[DUMP + lane - KK]; di = msi[DUMP + lane - KK]; }
    else                      { dv = -FLT_MAX;              di = 0x7fffffff; }
    size_t o = ((size_t)g * CHUNKS + c) * DUMP + lane;
    out_v[o] = dv; out_i[o] = di;
}

// ---------------- topk pass 2: merge 16x64 dumps per row, scatter ----------------
__global__ __launch_bounds__(64) void topk_merge(
    const float* __restrict__ in_v, const int* __restrict__ in_i,
    float* __restrict__ mask)
{
    __shared__ float msv[64 * KK];
    __shared__ int   msi[64 * KK];
    int g = blockIdx.x, lane = threadIdx.x;
    float v[KK]; int ix[KK];
    #pragma unroll
    for (int j = 0; j < KK; ++j) { v[j] = -FLT_MAX; ix[j] = 0x7fffffff; }
    const int total = CHUNKS * DUMP;   // 1024
    size_t rb = (size_t)g * total;
    for (int j = lane; j < total; j += 64)
        insert13(v, ix, in_v[rb + j], in_i[rb + j]);
    wave_merge13(msv, msi, lane, v, ix);
    if (lane < KK) mask[(size_t)g * AN + msi[lane]] = 1.0f;
}

// ---------------- fallbacks (small workspace) ----------------
__global__ __launch_bounds__(256) void argmax_kernel(
    const float* __restrict__ pd_scores,
    const float* __restrict__ pd_bboxes,
    const int*   __restrict__ gt_labels,
    const float* __restrict__ gt_bboxes,
    const float* __restrict__ scT, int use_t,
    float* __restrict__ out)
{
    __shared__ float4 gb[GN];
    __shared__ float  ga[GN];
    __shared__ int    gl[GN];
    int tid = threadIdx.x;
    for (int g = tid; g < GN; g += 256) {
        float4 b = reinterpret_cast<const float4*>(gt_bboxes)[g];
        gb[g] = b;
        ga[g] = (b.z - b.x) * (b.w - b.y);
        gl[g] = gt_labels[g];
    }
    __syncthreads();
    int a = blockIdx.x * 256 + tid;
    if (a >= AN) return;
    float4 pb = reinterpret_cast<const float4*>(pd_bboxes)[a];
    float pa = (pb.z - pb.x) * (pb.w - pb.y);
    float best = -1.0f; int bg = 0;
    for (int g = 0; g < GN; ++g) {
        int lab = gl[g];
        float sc = use_t ? scT[(size_t)lab * AN + a] : pd_scores[(size_t)a * NC + lab];
        float4 gbx = gb[g];
        float m = metric_f(gbx.x, gbx.y, gbx.z, gbx.w, ga[g],
                           pb.x, pb.y, pb.z, pb.w, pa, sc);
        if (m > best) { best = m; bg = g; }
    }
    out[a] = (best <= 0.0f) ? (float)NC : (float)gl[bg];
    reinterpret_cast<float4*>(out + AN)[a] = gb[bg];
    out[5 * AN + a] = best;
}

__global__ __launch_bounds__(256) void topk_kernel_fallback(
    const float* __restrict__ pd_scores,
    const float* __restrict__ pd_bboxes,
    const int*   __restrict__ gt_labels,
    const float* __restrict__ gt_bboxes,
    const float* __restrict__ scT, int use_t,
    float* __restrict__ mask)
{
    __shared__ float sv[256 * KK];
    __shared__ int   si[256 * KK];
    int g = blockIdx.x, tid = threadIdx.x;
    float4 b = reinterpret_cast<const float4*>(gt_bboxes)[g];
    float gax = (b.z - b.x) * (b.w - b.y);
    int lab = gt_labels[g];
    float v[KK]; int idx[KK];
    #pragma unroll
    for (int j = 0; j < KK; ++j) { v[j] = -FLT_MAX; idx[j] = 0x7fffffff; }
    for (int a = tid; a < AN; a += 256) {
        float4 pb = reinterpret_cast<const float4*>(pd_bboxes)[a];
        float pa = (pb.z - pb.x) * (pb.w - pb.y);
        float sc = use_t ? scT[(size_t)lab * AN + a] : pd_scores[(size_t)a * NC + lab];
        float m = metric_f(b.x, b.y, b.z, b.w, gax, pb.x, pb.y, pb.z, pb.w, pa, sc);
        insert13(v, idx, m, a);
    }
    #pragma unroll
    for (int j = 0; j < KK; ++j) { sv[tid * KK + j] = v[j]; si[tid * KK + j] = idx[j]; }
    for (int off = 128; off >= 1; off >>= 1) {
        __syncthreads();
        if (tid < off) {
            int i = 0, jj = 0;
            float ov[KK]; int oi[KK];
            #pragma unroll
            for (int t = 0; t < KK; ++t) {
                float va = sv[tid * KK + i];          int ia = si[tid * KK + i];
                float vb = sv[(tid + off) * KK + jj]; int ib = si[(tid + off) * KK + jj];
                bool ta = (va > vb) || (va == vb && ia < ib);
                ov[t] = ta ? va : vb; oi[t] = ta ? ia : ib;
                i += ta ? 1 : 0; jj += ta ? 0 : 1;
            }
            #pragma unroll
            for (int t = 0; t < KK; ++t) { sv[tid * KK + t] = ov[t]; si[tid * KK + t] = oi[t]; }
        }
    }
    __syncthreads();
    if (tid < KK) mask[(size_t)g * AN + si[tid]] = 1.0f;
}

extern "C" void kernel_launch(void* const* d_in, const int* in_sizes, int n_in,
                              void* d_out, int out_size, void* d_ws, size_t ws_size,
                              hipStream_t stream)
{
    const float* pd_scores = (const float*)d_in[0];
    const float* pd_bboxes = (const float*)d_in[1];
    const int*   gt_labels = (const int*)d_in[2];
    const float* gt_bboxes = (const float*)d_in[3];
    float* out  = (float*)d_out;
    float* mask = out + (size_t)6 * AN;

    hipMemsetAsync(mask, 0, (size_t)GN * AN * sizeof(float), stream);

    const size_t scT_b  = (size_t)NC * AN * sizeof(float);           // 32.0 MB
    const size_t auxn   = (size_t)GN * CHUNKS * DUMP;                // 524288
    const size_t aux_b  = auxn * 8;                                  // 4.2 MB
    const size_t part_b = (size_t)GSLICE * AN * sizeof(ull);         // 3.2 MB

    float* scT   = (float*)d_ws;
    float* aux_v = (float*)((char*)d_ws + scT_b);
    int*   aux_i = (int*)(aux_v + auxn);
    ull*   part  = (ull*)((char*)d_ws + scT_b + aux_b);

    if (ws_size >= scT_b + aux_b + part_b) {
        transpose_scores<<<(AN + 63) / 64, 256, 0, stream>>>(pd_scores, scT);
        topk_pass1<<<GN * CHUNKS / 4, 256, 0, stream>>>(
            pd_bboxes, gt_labels, gt_bboxes, scT, aux_v, aux_i);
        topk_merge<<<GN, 64, 0, stream>>>(aux_v, aux_i, mask);
        argmax_part<<<((AN + 255) / 256) * GSLICE, 256, 0, stream>>>(
            pd_bboxes, gt_labels, gt_bboxes, scT, part);
        argmax_combine<<<(AN + 255) / 256, 256, 0, stream>>>(
            part, gt_labels, gt_bboxes, out);
    } else if (ws_size >= scT_b + aux_b) {
        transpose_scores<<<(AN + 63) / 64, 256, 0, stream>>>(pd_scores, scT);
        topk_pass1<<<GN * CHUNKS / 4, 256, 0, stream>>>(
            pd_bboxes, gt_labels, gt_bboxes, scT, aux_v, aux_i);
        topk_merge<<<GN, 64, 0, stream>>>(aux_v, aux_i, mask);
        argmax_kernel<<<(AN + 255) / 256, 256, 0, stream>>>(
            pd_scores, pd_bboxes, gt_labels, gt_bboxes, scT, 1, out);
    } else if (ws_size >= scT_b) {
        transpose_scores<<<(AN + 63) / 64, 256, 0, stream>>>(pd_scores, scT);
        argmax_kernel<<<(AN + 255) / 256, 256, 0, stream>>>(
            pd_scores, pd_bboxes, gt_labels, gt_bboxes, scT, 1, out);
        topk_kernel_fallback<<<GN, 256, 0, stream>>>(
            pd_scores, pd_bboxes, gt_labels, gt_bboxes, scT, 1, mask);
    } else {
        argmax_kernel<<<(AN + 255) / 256, 256, 0, stream>>>(
            pd_scores, pd_bboxes, gt_labels, gt_bboxes, scT, 0, out);
        topk_kernel_fallback<<<GN, 256, 0, stream>>>(
            pd_scores, pd_bboxes, gt_labels, gt_bboxes, scT, 0, mask);
    }
}

// Round 5
// 183.931 us; speedup vs baseline: 4.0023x; 1.5502x over previous
//
#include <hip/hip_runtime.h>
#include <cfloat>
#include <cstdint>

#define AN 100000   // anchors
#define GN 512      // ground truths
#define NC 80       // classes
#define KK 13       // topk

#define CHUNKS 8
#define CH_LEN 12544              // 49*256; 7*12544=87808, last chunk 12192
#define DUMP 16                   // dump slots per (g, chunk): 13 + pad
#define GSLICE 4
#define GPS (GN / GSLICE)         // 128

typedef unsigned long long ull;

__device__ __forceinline__ float metric_f(
    float gx1, float gy1, float gx2, float gy2, float ga,
    float px1, float py1, float px2, float py2, float pa,
    float score)
{
    float ltx = fmaxf(gx1, px1), lty = fmaxf(gy1, py1);
    float rbx = fminf(gx2, px2), rby = fminf(gy2, py2);
    float w = fmaxf(rbx - ltx, 0.0f), h = fmaxf(rby - lty, 0.0f);
    float inter = w * h;
    float uni = ga + pa - inter;
    float iou = inter / (uni + 1e-9f);
    float i2 = iou * iou;
    float i6 = i2 * i2 * i2;
    return score * i6;   // scores ** 1.0 * ious ** 6.0
}

__device__ __forceinline__ float metric2(float4 g, float ga, float4 p, float sc)
{
    float pa = (p.z - p.x) * (p.w - p.y);
    return metric_f(g.x, g.y, g.z, g.w, ga, p.x, p.y, p.z, p.w, pa, sc);
}

// order-preserving float->uint map (total order; works for -FLT_MAX sentinel)
__device__ __forceinline__ unsigned f2ord(float f)
{
    unsigned b = __float_as_uint(f);
    return b ^ (unsigned)(((int)b >> 31) | 0x80000000);
}
__device__ __forceinline__ float ord2f(unsigned u)
{
    unsigned b = (u & 0x80000000u) ? (u ^ 0x80000000u) : ~u;
    return __uint_as_float(b);
}

// compare-swap: keep better (value desc, index asc) in (va, ia)
__device__ __forceinline__ void csw(float& va, int& ia, float& vb, int& ib)
{
    bool sw = (va < vb) || (va == vb && ia > ib);
    float tv = sw ? vb : va; int ti = sw ? ib : ia;
    vb = sw ? va : vb; ib = sw ? ia : ib;
    va = tv; ia = ti;
}

// wave-synchronous LDS fence
__device__ __forceinline__ void wsync()
{
    __builtin_amdgcn_sched_barrier(0);
    asm volatile("s_waitcnt lgkmcnt(0)" ::: "memory");
    __builtin_amdgcn_sched_barrier(0);
}

// Exact top-13 of {incumbents (lane r<13 holds rank r in inc_v/inc_i) ∪
// cand[0..n)}, n ≤ 511. Register-only: lane-strided load -> sort-8 ->
// incumbent merge -> 13 rounds of wave-argmax (u64 shfl_xor reduction).
// Post: lane r<13 holds rank r; returns the 13th-best value (new threshold).
__device__ float flush_x(int lane, int n, const float* cand_v, const int* cand_i,
                         float& inc_v, int& inc_i)
{
    wsync();                               // appended cand visible wave-wide
    float v[8]; int ix[8];
    #pragma unroll
    for (int k = 0; k < 8; ++k) {
        int j = lane + (k << 6);
        bool ok = j < n;
        v[k]  = ok ? cand_v[j] : -FLT_MAX;
        ix[k] = ok ? cand_i[j] : 0x7fffffff;
    }
    // Batcher odd-even mergesort, 8 inputs, 19 comparators (desc)
    csw(v[0],ix[0],v[1],ix[1]); csw(v[2],ix[2],v[3],ix[3]);
    csw(v[4],ix[4],v[5],ix[5]); csw(v[6],ix[6],v[7],ix[7]);
    csw(v[0],ix[0],v[2],ix[2]); csw(v[1],ix[1],v[3],ix[3]);
    csw(v[4],ix[4],v[6],ix[6]); csw(v[5],ix[5],v[7],ix[7]);
    csw(v[1],ix[1],v[2],ix[2]); csw(v[5],ix[5],v[6],ix[6]);
    csw(v[0],ix[0],v[4],ix[4]); csw(v[1],ix[1],v[5],ix[5]);
    csw(v[2],ix[2],v[6],ix[6]); csw(v[3],ix[3],v[7],ix[7]);
    csw(v[2],ix[2],v[4],ix[4]); csw(v[3],ix[3],v[5],ix[5]);
    csw(v[1],ix[1],v[2],ix[2]); csw(v[3],ix[3],v[4],ix[4]);
    csw(v[5],ix[5],v[6],ix[6]);
    // merge incumbent -> 9-deep sorted stream h[0..8]
    bool c[8];
    #pragma unroll
    for (int j = 0; j < 8; ++j)
        c[j] = (v[j] > inc_v) || (v[j] == inc_v && ix[j] < inc_i);
    float h[9]; int hi[9];
    h[0] = c[0] ? v[0] : inc_v;  hi[0] = c[0] ? ix[0] : inc_i;
    #pragma unroll
    for (int j = 1; j < 8; ++j) {
        h[j]  = c[j] ? v[j]  : (c[j-1] ? inc_v : v[j-1]);
        hi[j] = c[j] ? ix[j] : (c[j-1] ? inc_i : ix[j-1]);
    }
    h[8] = c[7] ? inc_v : v[7];  hi[8] = c[7] ? inc_i : ix[7];

    float th = -FLT_MAX;
    #pragma unroll
    for (int r = 0; r < KK; ++r) {
        ull myp = ((ull)f2ord(h[0]) << 32) | (unsigned)(~hi[0]);
        ull p = myp;
        #pragma unroll
        for (int o = 32; o >= 1; o >>= 1) {
            ull q = __shfl_xor(p, o);
            p = p > q ? p : q;
        }
        float wv = ord2f((unsigned)(p >> 32));
        int   wi = (int)~((unsigned)p);
        if (lane == r) { inc_v = wv; inc_i = wi; }
        bool pop = (myp == p);
        #pragma unroll
        for (int j = 0; j < 8; ++j) {
            h[j]  = pop ? h[j+1]  : h[j];
            hi[j] = pop ? hi[j+1] : hi[j];
        }
        h[8]  = pop ? -FLT_MAX   : h[8];
        hi[8] = pop ? 0x7fffffff : hi[8];
        th = wv;
    }
    return th;
}

// Insert (m, a) into a register-resident sorted-13 list (fallback kernels only).
__device__ __forceinline__ void insert13(float* v, int* ix, float m, int a)
{
    bool worse = (m < v[KK - 1]) || (m == v[KK - 1] && a > ix[KK - 1]);
    if (worse) return;
    int p = 0;
    #pragma unroll
    for (int j = 0; j < KK; ++j)
        p += ((v[j] > m) || (v[j] == m && ix[j] < a)) ? 1 : 0;
    #pragma unroll
    for (int j = KK - 1; j >= 1; --j) {
        bool sh = (j > p);
        v[j]  = sh ? v[j - 1]  : v[j];
        ix[j] = sh ? ix[j - 1] : ix[j];
    }
    #pragma unroll
    for (int j = 0; j < KK; ++j) if (j == p) { v[j] = m; ix[j] = a; }
}

// ---------------- pd_scores [AN][NC] -> scT [NC][AN] ----------------
__global__ __launch_bounds__(256) void transpose_scores(
    const float* __restrict__ ps, float* __restrict__ scT)
{
    __shared__ float tile[64][NC + 1];
    int a0 = blockIdx.x * 64;
    int tid = threadIdx.x;
    for (int i = tid; i < 64 * NC / 4; i += 256) {
        int fi = i * 4;
        int a = fi / NC, c = fi % NC;
        if (a0 + a < AN) {
            float4 v = *reinterpret_cast<const float4*>(ps + (size_t)(a0 + a) * NC + c);
            tile[a][c] = v.x; tile[a][c + 1] = v.y; tile[a][c + 2] = v.z; tile[a][c + 3] = v.w;
        }
    }
    __syncthreads();
    int j = tid & 63, cg = tid >> 6;
    int a = a0 + j;
    if (a < AN) {
        for (int c = cg; c < NC; c += 4)
            scT[(size_t)c * AN + a] = tile[j][c];
    }
}

// ---------------- argmax pass A1: per (anchor, g-slice) partial ----------------
__global__ __launch_bounds__(256) void argmax_part(
    const float* __restrict__ pd_bboxes,
    const int*   __restrict__ gt_labels,
    const float* __restrict__ gt_bboxes,
    const float* __restrict__ scT,
    ull* __restrict__ part)
{
    __shared__ float4 gb[GPS];
    __shared__ float  ga[GPS];
    __shared__ int    glb[GPS];
    int slice = blockIdx.x & (GSLICE - 1);
    int ab = (blockIdx.x >> 2) * 256;
    int tid = threadIdx.x;
    int g0 = slice * GPS;
    for (int i = tid; i < GPS; i += 256) {
        float4 bb = ((const float4*)gt_bboxes)[g0 + i];
        gb[i] = bb;
        ga[i] = (bb.z - bb.x) * (bb.w - bb.y);
        glb[i] = gt_labels[g0 + i];
    }
    __syncthreads();
    int a = ab + tid;
    if (a >= AN) return;
    float4 pb = ((const float4*)pd_bboxes)[a];
    float pa = (pb.z - pb.x) * (pb.w - pb.y);
    float best = -1.0f; int bg = 0;
    for (int i = 0; i < GPS; ++i) {
        float sc = scT[(size_t)glb[i] * AN + a];
        float4 gx = gb[i];
        float m = metric_f(gx.x, gx.y, gx.z, gx.w, ga[i],
                           pb.x, pb.y, pb.z, pb.w, pa, sc);
        if (m > best) { best = m; bg = i; }   // strict > => first-occurrence
    }
    ull pack = ((ull)__float_as_uint(best) << 32) | (ull)(0xFFFFFFFFu - (unsigned)(g0 + bg));
    part[(size_t)slice * AN + a] = pack;
}

// ---------------- argmax pass A2: combine 4 slices, write outputs ----------------
__global__ __launch_bounds__(256) void argmax_combine(
    const ull* __restrict__ part,
    const int* __restrict__ gt_labels,
    const float* __restrict__ gt_bboxes,
    float* __restrict__ out)
{
    int a = blockIdx.x * 256 + threadIdx.x;
    if (a >= AN) return;
    ull p0 = part[a], p1 = part[(size_t)AN + a];
    ull p2 = part[(size_t)2 * AN + a], p3 = part[(size_t)3 * AN + a];
    ull q0 = p0 > p1 ? p0 : p1;
    ull q1 = p2 > p3 ? p2 : p3;
    ull p = q0 > q1 ? q0 : q1;
    unsigned g = 0xFFFFFFFFu - (unsigned)(p & 0xFFFFFFFFull);
    float best = __uint_as_float((unsigned)(p >> 32));
    out[a] = (best <= 0.0f) ? (float)NC : (float)gt_labels[g];
    ((float4*)(out + AN))[a] = ((const float4*)gt_bboxes)[g];
    out[(size_t)5 * AN + a] = best;
}

// ---------------- topk pass 1 ----------------
// 4 independent waves/block, each owns one (g, chunk). Unit-stride loads:
// lane handles anchors {tb+lane, tb+64+lane, tb+128+lane, tb+192+lane}.
template<bool FULL>
__device__ __forceinline__ void tile256(
    int tb, int aend, int lane, uint64_t lt,
    const float4* __restrict__ pd4, const float* __restrict__ srow,
    float4 b, float gax, float& th, int& cnt,
    float* cand_v, int* cand_i, float& inc_v, int& inc_i)
{
    int a0 = tb + lane, a1 = a0 + 64, a2 = a0 + 128, a3 = a0 + 192;
    int c0 = FULL ? a0 : min(a0, AN - 1);
    int c1 = FULL ? a1 : min(a1, AN - 1);
    int c2 = FULL ? a2 : min(a2, AN - 1);
    int c3 = FULL ? a3 : min(a3, AN - 1);
    float4 B0 = pd4[c0], B1 = pd4[c1], B2 = pd4[c2], B3 = pd4[c3];
    float s0 = srow[c0], s1 = srow[c1], s2 = srow[c2], s3 = srow[c3];
    float m0 = metric2(b, gax, B0, s0);
    float m1 = metric2(b, gax, B1, s1);
    float m2 = metric2(b, gax, B2, s2);
    float m3 = metric2(b, gax, B3, s3);
    // strict >: an item equal to the current exact 13th always loses the
    // index tie (incumbent indices precede current-tile indices) — exact drop.
    bool h0 = (m0 > th) && (FULL || a0 < aend);
    bool h1 = (m1 > th) && (FULL || a1 < aend);
    bool h2 = (m2 > th) && (FULL || a2 < aend);
    bool h3 = (m3 > th) && (FULL || a3 < aend);
    if (__any(h0 | h1 | h2 | h3)) {
        uint64_t B;
        B = __ballot(h0);
        if (h0) { int p = cnt + __popcll(B & lt); cand_v[p] = m0; cand_i[p] = a0; }
        cnt += __popcll(B);
        B = __ballot(h1);
        if (h1) { int p = cnt + __popcll(B & lt); cand_v[p] = m1; cand_i[p] = a1; }
        cnt += __popcll(B);
        B = __ballot(h2);
        if (h2) { int p = cnt + __popcll(B & lt); cand_v[p] = m2; cand_i[p] = a2; }
        cnt += __popcll(B);
        B = __ballot(h3);
        if (h3) { int p = cnt + __popcll(B & lt); cand_v[p] = m3; cand_i[p] = a3; }
        cnt += __popcll(B);
        if (cnt >= 256) {             // cap: 255 + 256 = 511 < 512
            th = flush_x(lane, cnt, cand_v, cand_i, inc_v, inc_i);
            cnt = 0;
        }
    }
}

__global__ __launch_bounds__(256, 4) void topk_pass1(
    const float* __restrict__ pd_bboxes,
    const int*   __restrict__ gt_labels,
    const float* __restrict__ gt_bboxes,
    const float* __restrict__ scT,
    float* __restrict__ out_v, int* __restrict__ out_i)
{
    __shared__ float cvA[4][512];
    __shared__ int   ciA[4][512];
    int w = threadIdx.x >> 6, lane = threadIdx.x & 63;
    float* cand_v = cvA[w]; int* cand_i = ciA[w];
    uint64_t lt = (1ull << lane) - 1ull;
    int gid = blockIdx.x * 4 + w;
    int g = gid & (GN - 1), c = gid >> 9;

    float4 b = ((const float4*)gt_bboxes)[g];
    float gax = (b.z - b.x) * (b.w - b.y);
    int lab = gt_labels[g];
    const float* srow = scT + (size_t)lab * AN;
    const float4* pd4 = (const float4*)pd_bboxes;

    int base = c * CH_LEN;
    int len = min(CH_LEN, AN - base);
    int nfull = len >> 8, rem = len & 255;
    int aend = base + len;

    float th = -FLT_MAX; int cnt = 0;
    float inc_v = -FLT_MAX; int inc_i = 0x7fffffff;   // lane r<13: rank r

    for (int it = 0; it < nfull; ++it)
        tile256<true>(base + (it << 8), aend, lane, lt, pd4, srow,
                      b, gax, th, cnt, cand_v, cand_i, inc_v, inc_i);
    if (rem)
        tile256<false>(base + (nfull << 8), aend, lane, lt, pd4, srow,
                       b, gax, th, cnt, cand_v, cand_i, inc_v, inc_i);

    if (cnt > 0)
        flush_x(lane, cnt, cand_v, cand_i, inc_v, inc_i);

    if (lane < DUMP) {
        size_t o = ((size_t)g * CHUNKS + c) * DUMP + lane;
        out_v[o] = (lane < KK) ? inc_v : -FLT_MAX;
        out_i[o] = (lane < KK) ? inc_i : 0x7fffffff;
    }
}

// ---------------- topk pass 2: zero row + merge 8x16 dumps + scatter ----------------
__global__ __launch_bounds__(256) void topk_finalize(
    const float* __restrict__ in_v, const int* __restrict__ in_i,
    float* __restrict__ mask)
{
    int g = blockIdx.x, tid = threadIdx.x;
    float4* row4 = (float4*)(mask + (size_t)g * AN);
    float4 z = make_float4(0.f, 0.f, 0.f, 0.f);
    for (int j = tid; j < AN / 4; j += 256) row4[j] = z;
    __syncthreads();
    if (tid >= 64) return;
    int lane = tid;
    size_t rb = (size_t)g * (CHUNKS * DUMP);     // 128 entries
    float v0 = in_v[rb + lane], v1 = in_v[rb + 64 + lane];
    int   i0 = in_i[rb + lane], i1 = in_i[rb + 64 + lane];
    csw(v0, i0, v1, i1);
    #pragma unroll
    for (int r = 0; r < KK; ++r) {
        ull myp = ((ull)f2ord(v0) << 32) | (unsigned)(~i0);
        ull p = myp;
        #pragma unroll
        for (int o = 32; o >= 1; o >>= 1) {
            ull q = __shfl_xor(p, o);
            p = p > q ? p : q;
        }
        int wi = (int)~((unsigned)p);
        if (lane == r) mask[(size_t)g * AN + wi] = 1.0f;
        bool pop = (myp == p);
        v0 = pop ? v1 : v0;          i0 = pop ? i1 : i0;
        v1 = pop ? -FLT_MAX : v1;    i1 = pop ? 0x7fffffff : i1;
    }
}

// ---------------- fallbacks (small workspace) ----------------
__global__ __launch_bounds__(256) void argmax_kernel(
    const float* __restrict__ pd_scores,
    const float* __restrict__ pd_bboxes,
    const int*   __restrict__ gt_labels,
    const float* __restrict__ gt_bboxes,
    const float* __restrict__ scT, int use_t,
    float* __restrict__ out)
{
    __shared__ float4 gb[GN];
    __shared__ float  ga[GN];
    __shared__ int    gl[GN];
    int tid = threadIdx.x;
    for (int g = tid; g < GN; g += 256) {
        float4 b = reinterpret_cast<const float4*>(gt_bboxes)[g];
        gb[g] = b;
        ga[g] = (b.z - b.x) * (b.w - b.y);
        gl[g] = gt_labels[g];
    }
    __syncthreads();
    int a = blockIdx.x * 256 + tid;
    if (a >= AN) return;
    float4 pb = reinterpret_cast<const float4*>(pd_bboxes)[a];
    float pa = (pb.z - pb.x) * (pb.w - pb.y);
    float best = -1.0f; int bg = 0;
    for (int g = 0; g < GN; ++g) {
        int lab = gl[g];
        float sc = use_t ? scT[(size_t)lab * AN + a] : pd_scores[(size_t)a * NC + lab];
        float4 gbx = gb[g];
        float m = metric_f(gbx.x, gbx.y, gbx.z, gbx.w, ga[g],
                           pb.x, pb.y, pb.z, pb.w, pa, sc);
        if (m > best) { best = m; bg = g; }
    }
    out[a] = (best <= 0.0f) ? (float)NC : (float)gl[bg];
    reinterpret_cast<float4*>(out + AN)[a] = gb[bg];
    out[5 * AN + a] = best;
}

__global__ __launch_bounds__(256) void topk_kernel_fallback(
    const float* __restrict__ pd_scores,
    const float* __restrict__ pd_bboxes,
    const int*   __restrict__ gt_labels,
    const float* __restrict__ gt_bboxes,
    const float* __restrict__ scT, int use_t,
    float* __restrict__ mask)
{
    __shared__ float sv[256 * KK];
    __shared__ int   si[256 * KK];
    int g = blockIdx.x, tid = threadIdx.x;
    float4 b = reinterpret_cast<const float4*>(gt_bboxes)[g];
    float gax = (b.z - b.x) * (b.w - b.y);
    int lab = gt_labels[g];
    float v[KK]; int idx[KK];
    #pragma unroll
    for (int j = 0; j < KK; ++j) { v[j] = -FLT_MAX; idx[j] = 0x7fffffff; }
    for (int a = tid; a < AN; a += 256) {
        float4 pb = reinterpret_cast<const float4*>(pd_bboxes)[a];
        float pa = (pb.z - pb.x) * (pb.w - pb.y);
        float sc = use_t ? scT[(size_t)lab * AN + a] : pd_scores[(size_t)a * NC + lab];
        float m = metric_f(b.x, b.y, b.z, b.w, gax, pb.x, pb.y, pb.z, pb.w, pa, sc);
        insert13(v, idx, m, a);
    }
    #pragma unroll
    for (int j = 0; j < KK; ++j) { sv[tid * KK + j] = v[j]; si[tid * KK + j] = idx[j]; }
    for (int off = 128; off >= 1; off >>= 1) {
        __syncthreads();
        if (tid < off) {
            int i = 0, jj = 0;
            float ov[KK]; int oi[KK];
            #pragma unroll
            for (int t = 0; t < KK; ++t) {
                float va = sv[tid * KK + i];          int ia = si[tid * KK + i];
                float vb = sv[(tid + off) * KK + jj]; int ib = si[(tid + off) * KK + jj];
                bool ta = (va > vb) || (va == vb && ia < ib);
                ov[t] = ta ? va : vb; oi[t] = ta ? ia : ib;
                i += ta ? 1 : 0; jj += ta ? 0 : 1;
            }
            #pragma unroll
            for (int t = 0; t < KK; ++t) { sv[tid * KK + t] = ov[t]; si[tid * KK + t] = oi[t]; }
        }
    }
    __syncthreads();
    if (tid < KK) mask[(size_t)g * AN + si[tid]] = 1.0f;
}

extern "C" void kernel_launch(void* const* d_in, const int* in_sizes, int n_in,
                              void* d_out, int out_size, void* d_ws, size_t ws_size,
                              hipStream_t stream)
{
    const float* pd_scores = (const float*)d_in[0];
    const float* pd_bboxes = (const float*)d_in[1];
    const int*   gt_labels = (const int*)d_in[2];
    const float* gt_bboxes = (const float*)d_in[3];
    float* out  = (float*)d_out;
    float* mask = out + (size_t)6 * AN;

    const size_t scT_b  = (size_t)NC * AN * sizeof(float);           // 32.0 MB
    const size_t auxn   = (size_t)GN * CHUNKS * DUMP;                // 65536
    const size_t aux_b  = auxn * 8;                                  // 0.5 MB
    const size_t part_b = (size_t)GSLICE * AN * sizeof(ull);         // 3.2 MB

    float* scT   = (float*)d_ws;
    float* aux_v = (float*)((char*)d_ws + scT_b);
    int*   aux_i = (int*)(aux_v + auxn);
    ull*   part  = (ull*)((char*)d_ws + scT_b + aux_b);

    if (ws_size >= scT_b + aux_b + part_b) {
        transpose_scores<<<(AN + 63) / 64, 256, 0, stream>>>(pd_scores, scT);
        topk_pass1<<<GN * CHUNKS / 4, 256, 0, stream>>>(
            pd_bboxes, gt_labels, gt_bboxes, scT, aux_v, aux_i);
        topk_finalize<<<GN, 256, 0, stream>>>(aux_v, aux_i, mask);
        argmax_part<<<((AN + 255) / 256) * GSLICE, 256, 0, stream>>>(
            pd_bboxes, gt_labels, gt_bboxes, scT, part);
        argmax_combine<<<(AN + 255) / 256, 256, 0, stream>>>(
            part, gt_labels, gt_bboxes, out);
    } else if (ws_size >= scT_b + aux_b) {
        transpose_scores<<<(AN + 63) / 64, 256, 0, stream>>>(pd_scores, scT);
        topk_pass1<<<GN * CHUNKS / 4, 256, 0, stream>>>(
            pd_bboxes, gt_labels, gt_bboxes, scT, aux_v, aux_i);
        topk_finalize<<<GN, 256, 0, stream>>>(aux_v, aux_i, mask);
        argmax_kernel<<<(AN + 255) / 256, 256, 0, stream>>>(
            pd_scores, pd_bboxes, gt_labels, gt_bboxes, scT, 1, out);
    } else if (ws_size >= scT_b) {
        hipMemsetAsync(mask, 0, (size_t)GN * AN * sizeof(float), stream);
        transpose_scores<<<(AN + 63) / 64, 256, 0, stream>>>(pd_scores, scT);
        argmax_kernel<<<(AN + 255) / 256, 256, 0, stream>>>(
            pd_scores, pd_bboxes, gt_labels, gt_bboxes, scT, 1, out);
        topk_kernel_fallback<<<GN, 256, 0, stream>>>(
            pd_scores, pd_bboxes, gt_labels, gt_bboxes, scT, 1, mask);
    } else {
        hipMemsetAsync(mask, 0, (size_t)GN * AN * sizeof(float), stream);
        argmax_kernel<<<(AN + 255) / 256, 256, 0, stream>>>(
            pd_scores, pd_bboxes, gt_labels, gt_bboxes, scT, 0, out);
        topk_kernel_fallback<<<GN, 256, 0, stream>>>(
            pd_scores, pd_bboxes, gt_labels, gt_bboxes, scT, 0, mask);
    }
}